// Round 1
// baseline (3325.695 us; speedup 1.0000x reference)
//
#include <hip/hip_runtime.h>
#include <hip/hip_bf16.h>
#include <math.h>

#define Bsz 8
#define Dd  128
#define Tt  4096
#define Kk  1024
#define NQ  8
#define BT  (Bsz*Tt)   // 32768 points

// ---------------------------------------------------------------------------
// init: transpose x (B,D,T) -> resid (B,T,D); zero qout
// ---------------------------------------------------------------------------
__global__ void k_init(const float* __restrict__ x,
                       float* __restrict__ resid,
                       float* __restrict__ qout) {
    __shared__ float tile[32][33];
    int b  = blockIdx.z;
    int t0 = blockIdx.x * 32, d0 = blockIdx.y * 32;
    int tx = threadIdx.x, ty = threadIdx.y;   // 32 x 8
    #pragma unroll
    for (int k = 0; k < 4; k++) {
        int d = d0 + ty + k * 8;
        tile[ty + k * 8][tx] = x[(b * Dd + d) * Tt + t0 + tx];
    }
    __syncthreads();
    #pragma unroll
    for (int k = 0; k < 4; k++) {
        int t = t0 + ty + k * 8;
        int o = (b * Tt + t) * Dd + d0 + tx;
        resid[o] = tile[tx][ty + k * 8];
        qout[o]  = 0.0f;
    }
}

// ---------------------------------------------------------------------------
// c2[q][k] = sum_d cb[q][k][d]^2 ; also zero the commit accumulators
// one wave per codebook row
// ---------------------------------------------------------------------------
__global__ void k_c2(const float* __restrict__ cb,
                     float* __restrict__ c2,
                     double* __restrict__ commits) {
    int row  = blockIdx.x * 4 + (threadIdx.x >> 6);
    int lane = threadIdx.x & 63;
    const float* p = cb + (size_t)row * Dd;
    float a = p[lane], b = p[lane + 64];
    float s = a * a + b * b;
    #pragma unroll
    for (int off = 32; off; off >>= 1) s += __shfl_down(s, off);
    if (lane == 0) c2[row] = s;
    if (blockIdx.x == 0 && threadIdx.x < NQ) commits[threadIdx.x] = 0.0;
}

// ---------------------------------------------------------------------------
// argmin over K=1024 codes for 64 points per block.
// threads 256 = 16 (i: point-group) x 16 (j: code-group), 4x4 micro-tile.
// LDS layouts transposed: Rt[k][point], Ct[k][code] -> float4 reads over the
// tile dim: 2 ds_read_b128 per 16 FMA (VALU-bound).
// score = c2 - 2*dot (||r||^2 constant per point, argmin-invariant).
// ---------------------------------------------------------------------------
__global__ __launch_bounds__(256) void k_argmin(
        const float* __restrict__ resid,
        const float* __restrict__ cb,     // this stage's codebook (K x D)
        const float* __restrict__ c2,     // this stage's c2 (K)
        int*   __restrict__ idxo,
        float* __restrict__ codes_f) {
    __shared__ float Rt[Dd][68];   // [k][point]  34816 B
    __shared__ float Ct[32][68];   // [kk][code]   8704 B
    __shared__ float redv[64][17]; //              4352 B
    __shared__ int   redi[64][17]; //              4352 B

    int tid  = threadIdx.x;
    int base = blockIdx.x * 64;    // first point of this block

    // stage residual tile: 64 points x 128 dims
    #pragma unroll
    for (int r = 0; r < 32; r++) {
        int flat = r * 256 + tid;
        int p = flat >> 7, d = flat & 127;
        Rt[d][p] = resid[(size_t)(base + p) * Dd + d];
    }

    int i = tid >> 4;    // point group: points 4i..4i+3
    int j = tid & 15;    // code group within chunk: codes 4j..4j+3

    float best[4]; int bidx[4];
    #pragma unroll
    for (int pp = 0; pp < 4; pp++) { best[pp] = INFINITY; bidx[pp] = 0; }

    __syncthreads();

    for (int chunk = 0; chunk < 16; chunk++) {        // 64 codes per chunk
        float acc[4][4] = {};
        for (int ks = 0; ks < 4; ks++) {              // k-slices of 32
            __syncthreads();
            #pragma unroll
            for (int r = 0; r < 8; r++) {             // load 64 codes x 32 k
                int flat = r * 256 + tid;
                int c = flat >> 5, k = flat & 31;
                Ct[k][c] = cb[(size_t)(chunk * 64 + c) * Dd + ks * 32 + k];
            }
            __syncthreads();
            #pragma unroll
            for (int kk = 0; kk < 32; kk++) {
                float4 rv = *(const float4*)&Rt[ks * 32 + kk][i * 4];
                float4 cv = *(const float4*)&Ct[kk][j * 4];
                acc[0][0] += rv.x * cv.x; acc[0][1] += rv.x * cv.y;
                acc[0][2] += rv.x * cv.z; acc[0][3] += rv.x * cv.w;
                acc[1][0] += rv.y * cv.x; acc[1][1] += rv.y * cv.y;
                acc[1][2] += rv.y * cv.z; acc[1][3] += rv.y * cv.w;
                acc[2][0] += rv.z * cv.x; acc[2][1] += rv.z * cv.y;
                acc[2][2] += rv.z * cv.z; acc[2][3] += rv.z * cv.w;
                acc[3][0] += rv.w * cv.x; acc[3][1] += rv.w * cv.y;
                acc[3][2] += rv.w * cv.z; acc[3][3] += rv.w * cv.w;
            }
        }
        // chunk epilogue: codes scanned in ascending order per thread,
        // strict < keeps the first occurrence (jnp.argmin semantics)
        #pragma unroll
        for (int cc = 0; cc < 4; cc++) {
            int code = chunk * 64 + j * 4 + cc;
            float cv2 = c2[code];
            #pragma unroll
            for (int pp = 0; pp < 4; pp++) {
                float s = cv2 - 2.0f * acc[pp][cc];
                if (s < best[pp]) { best[pp] = s; bidx[pp] = code; }
            }
        }
    }

    // cross-j reduction (16 candidates per point), tie-break to smaller index
    #pragma unroll
    for (int pp = 0; pp < 4; pp++) {
        redv[i * 4 + pp][j] = best[pp];
        redi[i * 4 + pp][j] = bidx[pp];
    }
    __syncthreads();
    if (tid < 64) {
        float bv = redv[tid][0]; int bi = redi[tid][0];
        #pragma unroll
        for (int j2 = 1; j2 < 16; j2++) {
            float v = redv[tid][j2]; int ix = redi[tid][j2];
            if (v < bv || (v == bv && ix < bi)) { bv = v; bi = ix; }
        }
        idxo[base + tid]    = bi;
        codes_f[base + tid] = (float)bi;
    }
}

// ---------------------------------------------------------------------------
// residual / qout update with straight-through estimator, replicating the
// reference's exact f32 op order; commit-loss partial sum per stage.
// ---------------------------------------------------------------------------
__global__ void k_update(float* __restrict__ resid,
                         float* __restrict__ qout,
                         const float* __restrict__ cb,
                         const int* __restrict__ idx,
                         double* __restrict__ commit) {
    int gid = blockIdx.x * 256 + threadIdx.x;
    int pt = gid >> 7, d = gid & 127;
    int ix = idx[pt];
    float r  = resid[gid];
    float q  = cb[(size_t)ix * Dd + d];
    float t1  = q - r;        // q - residual
    float qst = r + t1;       // straight-through forward value
    resid[gid] = r - qst;     // new residual
    qout[gid] += qst;
    float v = t1 * t1;
    #pragma unroll
    for (int off = 32; off; off >>= 1) v += __shfl_down(v, off);
    __shared__ float wsum[4];
    int lane = threadIdx.x & 63, w = threadIdx.x >> 6;
    if (lane == 0) wsum[w] = v;
    __syncthreads();
    if (threadIdx.x == 0)
        atomicAdd(commit, (double)(wsum[0] + wsum[1] + wsum[2] + wsum[3]));
}

// ---------------------------------------------------------------------------
// final: transpose qout (B,T,D) -> quantized (B,D,T)
// ---------------------------------------------------------------------------
__global__ void k_final(const float* __restrict__ qout,
                        float* __restrict__ outq) {
    __shared__ float tile[32][33];
    int b  = blockIdx.z;
    int t0 = blockIdx.x * 32, d0 = blockIdx.y * 32;
    int tx = threadIdx.x, ty = threadIdx.y;   // 32 x 8
    #pragma unroll
    for (int k = 0; k < 4; k++) {
        int t = t0 + ty + k * 8;
        tile[ty + k * 8][tx] = qout[(b * Tt + t) * Dd + d0 + tx];
    }
    __syncthreads();
    #pragma unroll
    for (int k = 0; k < 4; k++) {
        int d = d0 + ty + k * 8;
        outq[(b * Dd + d) * Tt + t0 + tx] = tile[tx][ty + k * 8];
    }
}

// ---------------------------------------------------------------------------
// scalars: bw = n_q * log2(K) * frame_rate ; penalty = mean(commits)
// ---------------------------------------------------------------------------
__global__ void k_scalars(const double* __restrict__ commits,
                          const int* __restrict__ frame_rate,
                          float* __restrict__ outs) {
    if (threadIdx.x == 0 && blockIdx.x == 0) {
        double s = 0.0;
        #pragma unroll
        for (int q = 0; q < NQ; q++) s += commits[q];
        double per_elem = s / ((double)NQ * (double)BT * (double)Dd);
        outs[0] = (float)(NQ * 10.0 * (double)frame_rate[0]); // log2(1024)=10
        outs[1] = (float)per_elem;
    }
}

extern "C" void kernel_launch(void* const* d_in, const int* in_sizes, int n_in,
                              void* d_out, int out_size, void* d_ws, size_t ws_size,
                              hipStream_t stream) {
    const float* x   = (const float*)d_in[0];   // (B, D, T)
    const float* cb  = (const float*)d_in[1];   // (NQ, K, D)
    const int*   fr  = (const int*)d_in[2];     // frame_rate scalar

    float* outq    = (float*)d_out;             // quantized (B,D,T): 4194304
    float* codes_f = outq + (size_t)Bsz * Dd * Tt;   // codes (NQ,B,T): 262144
    float* scal    = codes_f + (size_t)NQ * BT;      // bw, penalty

    // workspace layout (all 8-byte aligned)
    char* ws = (char*)d_ws;
    float*  resid   = (float*)ws;                         // BT*D f32
    float*  qout    = resid + (size_t)BT * Dd;            // BT*D f32
    float*  c2      = qout + (size_t)BT * Dd;             // NQ*K f32
    int*    idx     = (int*)(c2 + (size_t)NQ * Kk);       // BT i32
    double* commits = (double*)(idx + BT);                // NQ f64

    dim3 tb(32, 8, 1);
    k_init<<<dim3(Tt / 32, Dd / 32, Bsz), tb, 0, stream>>>(x, resid, qout);
    k_c2<<<NQ * Kk / 4, 256, 0, stream>>>(cb, c2, commits);

    for (int q = 0; q < NQ; q++) {
        k_argmin<<<BT / 64, 256, 0, stream>>>(
            resid, cb + (size_t)q * Kk * Dd, c2 + (size_t)q * Kk,
            idx, codes_f + (size_t)q * BT);
        k_update<<<(BT * Dd) / 256, 256, 0, stream>>>(
            resid, qout, cb + (size_t)q * Kk * Dd, idx, commits + q);
    }

    k_final<<<dim3(Tt / 32, Dd / 32, Bsz), tb, 0, stream>>>(qout, outq);
    k_scalars<<<1, 64, 0, stream>>>(commits, fr, scal);
}

// Round 2
// 2109.239 us; speedup vs baseline: 1.5767x; 1.5767x over previous
//
#include <hip/hip_runtime.h>
#include <math.h>

#define Bsz 8
#define Dd  128
#define Tt  4096
#define Kk  1024
#define NQ  8
#define BT  (Bsz*Tt)        // 32768 points
#define KSPLIT 8
#define KSLICE (Kk/KSPLIT)  // 128 codes per argmin block

// ---------------------------------------------------------------------------
// init: transpose x (B,D,T) -> resid (B,T,D)
// ---------------------------------------------------------------------------
__global__ void k_init(const float* __restrict__ x,
                       float* __restrict__ resid) {
    __shared__ float tile[32][33];
    int b  = blockIdx.z;
    int t0 = blockIdx.x * 32, d0 = blockIdx.y * 32;
    int tx = threadIdx.x, ty = threadIdx.y;   // 32 x 8
    #pragma unroll
    for (int k = 0; k < 4; k++) {
        int d = d0 + ty + k * 8;
        tile[ty + k * 8][tx] = x[((size_t)(b * Dd + d)) * Tt + t0 + tx];
    }
    __syncthreads();
    #pragma unroll
    for (int k = 0; k < 4; k++) {
        int t = t0 + ty + k * 8;
        resid[((size_t)(b * Tt + t)) * Dd + d0 + tx] = tile[tx][ty + k * 8];
    }
}

// ---------------------------------------------------------------------------
// cbT[q][d][k] = cb[q][k][d]  (once; static across stages)
// ---------------------------------------------------------------------------
__global__ void k_cbT(const float* __restrict__ cb, float* __restrict__ cbT) {
    __shared__ float tile[32][33];
    int q  = blockIdx.z;
    int k0 = blockIdx.x * 32, d0 = blockIdx.y * 32;
    int tx = threadIdx.x, ty = threadIdx.y;   // 32 x 8
    const float* src = cb  + (size_t)q * Kk * Dd;
    float*       dst = cbT + (size_t)q * Dd * Kk;
    #pragma unroll
    for (int r = 0; r < 4; r++) {
        int k = k0 + ty + r * 8;
        tile[ty + r * 8][tx] = src[(size_t)k * Dd + d0 + tx];
    }
    __syncthreads();
    #pragma unroll
    for (int r = 0; r < 4; r++) {
        int d = d0 + ty + r * 8;
        dst[(size_t)d * Kk + k0 + tx] = tile[tx][ty + r * 8];
    }
}

// ---------------------------------------------------------------------------
// c2[q][k] = sum_d cb[q][k][d]^2 ; zero commit accumulators
// ---------------------------------------------------------------------------
__global__ void k_c2(const float* __restrict__ cb,
                     float* __restrict__ c2,
                     double* __restrict__ commits) {
    int row  = blockIdx.x * 4 + (threadIdx.x >> 6);
    int lane = threadIdx.x & 63;
    const float* p = cb + (size_t)row * Dd;
    float a = p[lane], b = p[lane + 64];
    float s = a * a + b * b;
    #pragma unroll
    for (int off = 32; off; off >>= 1) s += __shfl_down(s, off);
    if (lane == 0) c2[row] = s;
    if (blockIdx.x == 0 && threadIdx.x < NQ) commits[threadIdx.x] = 0.0;
}

// ---------------------------------------------------------------------------
// partial argmin: 64 points x 128 codes per block (8-way K-split).
// LDS 26112 B -> 6 blocks/CU. Same f32 arithmetic + tie order as round 1.
// ---------------------------------------------------------------------------
__global__ __launch_bounds__(256, 6) void k_argmin_part(
        const float* __restrict__ resid,
        const float* __restrict__ cbT,    // this stage's (D x K) codebook
        const float* __restrict__ c2,     // this stage's c2 (K)
        float* __restrict__ pval,         // (BT, KSPLIT)
        int*   __restrict__ pidx) {
    __shared__ float Rt[64][68];          // [dim-in-half][point] 17408 B
    __shared__ union USh {
        float ct[32][64];                 // [k][code] 8192 B
        struct { float v[64][17]; int ix[64][17]; } red; // 8704 B
    } sh;

    int tid      = threadIdx.x;
    int ksl      = blockIdx.x & (KSPLIT - 1);
    int base     = (blockIdx.x >> 3) * 64;
    int codeBase = ksl * KSLICE;

    int i = tid >> 4;     // point group (4 pts)
    int j = tid & 15;     // code group (4 codes)

    float best[4]; int bidx[4];
    #pragma unroll
    for (int pp = 0; pp < 4; pp++) { best[pp] = INFINITY; bidx[pp] = codeBase; }

    for (int chunk = 0; chunk < 2; chunk++) {       // 64 codes per chunk
        float acc[4][4] = {};
        for (int kph = 0; kph < 2; kph++) {         // 64-dim halves
            for (int ks = 0; ks < 2; ks++) {        // 32-dim slices
                __syncthreads();
                {   // stage Ct: 32 k x 64 codes, coalesced + conflict-free
                    int kbase = kph * 64 + ks * 32;
                    #pragma unroll
                    for (int r = 0; r < 2; r++) {
                        int f4 = r * 256 + tid;
                        int k = f4 >> 4, c4 = f4 & 15;
                        float4 v = *(const float4*)&cbT[(size_t)(kbase + k) * Kk
                                                        + codeBase + chunk * 64 + c4 * 4];
                        *(float4*)&sh.ct[k][c4 * 4] = v;
                    }
                }
                if (ks == 0) {  // stage Rt: 64 pts x 64 dims of this half
                    #pragma unroll
                    for (int r = 0; r < 4; r++) {
                        int f4 = r * 256 + tid;
                        int p = f4 >> 4, d4 = f4 & 15;
                        float4 v = *(const float4*)&resid[(size_t)(base + p) * Dd
                                                          + kph * 64 + d4 * 4];
                        Rt[d4 * 4 + 0][p] = v.x; Rt[d4 * 4 + 1][p] = v.y;
                        Rt[d4 * 4 + 2][p] = v.z; Rt[d4 * 4 + 3][p] = v.w;
                    }
                }
                __syncthreads();
                #pragma unroll
                for (int kk = 0; kk < 32; kk++) {
                    float4 rv = *(const float4*)&Rt[ks * 32 + kk][i * 4];
                    float4 cv = *(const float4*)&sh.ct[kk][j * 4];
                    acc[0][0] += rv.x * cv.x; acc[0][1] += rv.x * cv.y;
                    acc[0][2] += rv.x * cv.z; acc[0][3] += rv.x * cv.w;
                    acc[1][0] += rv.y * cv.x; acc[1][1] += rv.y * cv.y;
                    acc[1][2] += rv.y * cv.z; acc[1][3] += rv.y * cv.w;
                    acc[2][0] += rv.z * cv.x; acc[2][1] += rv.z * cv.y;
                    acc[2][2] += rv.z * cv.z; acc[2][3] += rv.z * cv.w;
                    acc[3][0] += rv.w * cv.x; acc[3][1] += rv.w * cv.y;
                    acc[3][2] += rv.w * cv.z; acc[3][3] += rv.w * cv.w;
                }
            }
        }
        // chunk epilogue: ascending code scan, strict < = first occurrence
        #pragma unroll
        for (int cc = 0; cc < 4; cc++) {
            int code = codeBase + chunk * 64 + j * 4 + cc;
            float cv2 = c2[code];
            #pragma unroll
            for (int pp = 0; pp < 4; pp++) {
                float s = cv2 - 2.0f * acc[pp][cc];
                if (s < best[pp]) { best[pp] = s; bidx[pp] = code; }
            }
        }
    }

    __syncthreads();   // done reading sh.ct; reuse as reduction space
    #pragma unroll
    for (int pp = 0; pp < 4; pp++) {
        sh.red.v[i * 4 + pp][j]  = best[pp];
        sh.red.ix[i * 4 + pp][j] = bidx[pp];
    }
    __syncthreads();
    if (tid < 64) {
        float bv = sh.red.v[tid][0]; int bi = sh.red.ix[tid][0];
        #pragma unroll
        for (int j2 = 1; j2 < 16; j2++) {
            float v = sh.red.v[tid][j2]; int ix = sh.red.ix[tid][j2];
            if (v < bv || (v == bv && ix < bi)) { bv = v; bi = ix; }
        }
        pval[(size_t)(base + tid) * KSPLIT + ksl] = bv;
        pidx[(size_t)(base + tid) * KSPLIT + ksl] = bi;
    }
}

// ---------------------------------------------------------------------------
// combine partials + residual STE update + commit partial. 16 points/block.
// halves are ascending code ranges -> strict < keeps first-occurrence argmin.
// ---------------------------------------------------------------------------
__global__ __launch_bounds__(256) void k_combine_update(
        float* __restrict__ resid,
        const float* __restrict__ cb,     // this stage's (K x D) codebook
        const float* __restrict__ pval,
        const int*   __restrict__ pidx,
        float* __restrict__ codes_f,      // already offset by q*BT
        double* __restrict__ commit) {
    __shared__ int   sidx[16];
    __shared__ float wsum[4];
    int tid  = threadIdx.x;
    int base = blockIdx.x * 16;

    if (tid < 16) {
        int p = base + tid;
        const float* pv = pval + (size_t)p * KSPLIT;
        const int*   pi = pidx + (size_t)p * KSPLIT;
        float bv = pv[0]; int bi = pi[0];
        #pragma unroll
        for (int h = 1; h < KSPLIT; h++) {
            float v = pv[h];
            if (v < bv) { bv = v; bi = pi[h]; }
        }
        sidx[tid]  = bi;
        codes_f[p] = (float)bi;
    }
    __syncthreads();

    int d = tid & 127, po = tid >> 7;
    float cacc = 0.0f;
    #pragma unroll
    for (int it = 0; it < 8; it++) {
        int p = it * 2 + po;
        size_t g = (size_t)(base + p) * Dd + d;
        float r  = resid[g];
        float qv = cb[(size_t)sidx[p] * Dd + d];
        float t1  = qv - r;       // q - residual
        float qst = r + t1;       // straight-through value
        resid[g]  = r - qst;      // next residual
        cacc += t1 * t1;
    }
    #pragma unroll
    for (int off = 32; off; off >>= 1) cacc += __shfl_down(cacc, off);
    int lane = tid & 63, w = tid >> 6;
    if (lane == 0) wsum[w] = cacc;
    __syncthreads();
    if (tid == 0)
        atomicAdd(commit, (double)(wsum[0] + wsum[1] + wsum[2] + wsum[3]));
}

// ---------------------------------------------------------------------------
// final: out(B,D,T) = x - resid_final^T
// ---------------------------------------------------------------------------
__global__ void k_final(const float* __restrict__ x,
                        const float* __restrict__ resid,
                        float* __restrict__ outq) {
    __shared__ float tile[32][33];
    int b  = blockIdx.z;
    int t0 = blockIdx.x * 32, d0 = blockIdx.y * 32;
    int tx = threadIdx.x, ty = threadIdx.y;   // 32 x 8
    #pragma unroll
    for (int k = 0; k < 4; k++) {
        int t = t0 + ty + k * 8;
        tile[ty + k * 8][tx] = resid[((size_t)(b * Tt + t)) * Dd + d0 + tx];
    }
    __syncthreads();
    #pragma unroll
    for (int k = 0; k < 4; k++) {
        int d = d0 + ty + k * 8;
        size_t o = ((size_t)(b * Dd + d)) * Tt + t0 + tx;
        outq[o] = x[o] - tile[tx][ty + k * 8];
    }
}

// ---------------------------------------------------------------------------
// scalars
// ---------------------------------------------------------------------------
__global__ void k_scalars(const double* __restrict__ commits,
                          const int* __restrict__ frame_rate,
                          float* __restrict__ outs) {
    if (threadIdx.x == 0 && blockIdx.x == 0) {
        double s = 0.0;
        #pragma unroll
        for (int q = 0; q < NQ; q++) s += commits[q];
        double per_elem = s / ((double)NQ * (double)BT * (double)Dd);
        outs[0] = (float)(NQ * 10.0 * (double)frame_rate[0]); // log2(1024)=10
        outs[1] = (float)per_elem;
    }
}

extern "C" void kernel_launch(void* const* d_in, const int* in_sizes, int n_in,
                              void* d_out, int out_size, void* d_ws, size_t ws_size,
                              hipStream_t stream) {
    const float* x  = (const float*)d_in[0];   // (B, D, T)
    const float* cb = (const float*)d_in[1];   // (NQ, K, D)
    const int*   fr = (const int*)d_in[2];     // frame_rate

    float* outq    = (float*)d_out;                       // (B,D,T) 4194304
    float* codes_f = outq + (size_t)Bsz * Dd * Tt;        // (NQ,B,T) 262144
    float* scal    = codes_f + (size_t)NQ * BT;           // bw, penalty

    char* ws = (char*)d_ws;
    float*  resid   = (float*)ws;                             // BT*D
    float*  cbT     = resid + (size_t)BT * Dd;                // NQ*D*K
    float*  c2      = cbT + (size_t)NQ * Dd * Kk;             // NQ*K
    float*  pval    = c2 + (size_t)NQ * Kk;                   // BT*KSPLIT
    int*    pidx    = (int*)(pval + (size_t)BT * KSPLIT);     // BT*KSPLIT
    double* commits = (double*)(pidx + (size_t)BT * KSPLIT);  // NQ

    dim3 tb(32, 8, 1);
    k_init<<<dim3(Tt / 32, Dd / 32, Bsz), tb, 0, stream>>>(x, resid);
    k_cbT<<<dim3(Kk / 32, Dd / 32, NQ), tb, 0, stream>>>(cb, cbT);
    k_c2<<<NQ * Kk / 4, 256, 0, stream>>>(cb, c2, commits);

    for (int q = 0; q < NQ; q++) {
        k_argmin_part<<<(BT / 64) * KSPLIT, 256, 0, stream>>>(
            resid, cbT + (size_t)q * Dd * Kk, c2 + (size_t)q * Kk, pval, pidx);
        k_combine_update<<<BT / 16, 256, 0, stream>>>(
            resid, cb + (size_t)q * Kk * Dd, pval, pidx,
            codes_f + (size_t)q * BT, commits + q);
    }

    k_final<<<dim3(Tt / 32, Dd / 32, Bsz), tb, 0, stream>>>(x, resid, outq);
    k_scalars<<<1, 64, 0, stream>>>(commits, fr, scal);
}